// Round 1
// baseline (1826.799 us; speedup 1.0000x reference)
//
#include <hip/hip_runtime.h>
#include <hip/hip_bf16.h>
#include <math.h>

#define N_EXPERTS 8
#define TOPK      2
#define IN_DIM    512
#define HID_DIM   1024
#define OUT_DIM   512
#define B_TOKENS  16384
#define NPAIRS    (B_TOKENS * TOPK)   // 32768 token-expert pairs (fixed!)
#define MAX_RB    264                 // max 128-row blocks after per-expert pad
#define MAX_ROWS  (MAX_RB * 128)      // 33792

typedef __attribute__((ext_vector_type(8))) short short8;   // 8 bf16
typedef __attribute__((ext_vector_type(4))) float floatx4;

// ---- workspace layout (bytes) ----
#define WS_CNT     0          // 8 int
#define WS_CURSOR  32         // 8 int
#define WS_OFFS    64         // 9 int
#define WS_RBE     128        // 264 int
#define WS_TKIDX   1280       // 32768 int
#define WS_TKW     132352     // 32768 float
#define WS_ROWS    263424     // 33792 int
#define WS_WPOS    398592     // 33792 float
#define WS_W1T     533760     // 8*1024*512 bf16 = 8 MB
#define WS_W2T     8922368    // 8*512*1024 bf16 = 8 MB
#define WS_XG      17310976   // 33792*512 bf16  = 34.6 MB
#define WS_H       51913984   // 33792*1024 bf16 = 69.2 MB
// total ~121.2 MB

__device__ __forceinline__ short f2bf(float f) {
  unsigned u = __float_as_uint(f);
  unsigned r = (u + 0x7fffu + ((u >> 16) & 1u)) >> 16;  // RNE
  return (short)r;
}

__device__ __forceinline__ void async16(const void* g, void* l) {
  __builtin_amdgcn_global_load_lds(
      (const __attribute__((address_space(1))) unsigned*)g,
      (__attribute__((address_space(3))) unsigned*)l, 16, 0, 0);
}

// ---------------- weight transpose + fp32->bf16 ----------------
// src [E][R][C] fp32 -> dst [E][C][R] bf16
__global__ __launch_bounds__(256) void transpose_cvt(const float* __restrict__ src,
                                                     short* __restrict__ dst,
                                                     int R, int C) {
  __shared__ float tile[32][33];
  int e = blockIdx.z;
  int r0 = blockIdx.y * 32, c0 = blockIdx.x * 32;
  const float* s = src + (size_t)e * R * C;
  short* d = dst + (size_t)e * R * C;
  int tr = threadIdx.x >> 5, tc = threadIdx.x & 31;
#pragma unroll
  for (int j = 0; j < 4; ++j)
    tile[tr + j * 8][tc] = s[(size_t)(r0 + tr + j * 8) * C + c0 + tc];
  __syncthreads();
#pragma unroll
  for (int j = 0; j < 4; ++j)
    d[(size_t)(c0 + tr + j * 8) * R + r0 + tc] = f2bf(tile[tc][tr + j * 8]);
}

// ---------------- gate: fp32 scores, top-2, softmax, counts ----------------
__global__ __launch_bounds__(256) void gate_kernel(const float* __restrict__ x,
                                                   const float* __restrict__ gw,
                                                   const float* __restrict__ gb,
                                                   int* __restrict__ tkidx,
                                                   float* __restrict__ tkw,
                                                   int* __restrict__ cnt) {
  __shared__ int lds_cnt[N_EXPERTS];
  if (threadIdx.x < N_EXPERTS) lds_cnt[threadIdx.x] = 0;
  __syncthreads();
  int w = threadIdx.x >> 6, lane = threadIdx.x & 63;
#pragma unroll 1
  for (int q = 0; q < 4; ++q) {
    int t = blockIdx.x * 16 + w * 4 + q;
    float s[8] = {0.f, 0.f, 0.f, 0.f, 0.f, 0.f, 0.f, 0.f};
#pragma unroll
    for (int it = 0; it < 8; ++it) {
      int i = it * 64 + lane;
      float xv = x[(size_t)t * IN_DIM + i];
      const float4* gwr = (const float4*)(gw + (size_t)i * 8);
      float4 g0 = gwr[0], g1 = gwr[1];
      s[0] += xv * g0.x; s[1] += xv * g0.y; s[2] += xv * g0.z; s[3] += xv * g0.w;
      s[4] += xv * g1.x; s[5] += xv * g1.y; s[6] += xv * g1.z; s[7] += xv * g1.w;
    }
#pragma unroll
    for (int off = 32; off > 0; off >>= 1) {
#pragma unroll
      for (int j = 0; j < 8; ++j) s[j] += __shfl_xor(s[j], off);
    }
    if (lane == 0) {
      float v[8];
#pragma unroll
      for (int j = 0; j < 8; ++j) v[j] = s[j] + gb[j];
      int i1 = 0; float v1 = v[0];
#pragma unroll
      for (int j = 1; j < 8; ++j) if (v[j] > v1) { v1 = v[j]; i1 = j; }
      int i2 = -1; float v2 = -1e30f;
#pragma unroll
      for (int j = 0; j < 8; ++j) if (j != i1 && v[j] > v2) { v2 = v[j]; i2 = j; }
      float ex = expf(v2 - v1);
      float wa = 1.0f / (1.0f + ex);
      tkidx[t * 2] = i1; tkidx[t * 2 + 1] = i2;
      tkw[t * 2] = wa;  tkw[t * 2 + 1] = ex * wa;
      atomicAdd(&lds_cnt[i1], 1); atomicAdd(&lds_cnt[i2], 1);
    }
  }
  __syncthreads();
  if (threadIdx.x < N_EXPERTS) atomicAdd(&cnt[threadIdx.x], lds_cnt[threadIdx.x]);
}

// ---------------- offsets (padded), rb->expert map, pad-entry zero, aux ----------------
__global__ __launch_bounds__(256) void offsets_kernel(const int* __restrict__ cnt,
                                                      int* __restrict__ offs,
                                                      int* __restrict__ rbe,
                                                      int* __restrict__ rows,
                                                      float* __restrict__ wpos,
                                                      float* __restrict__ aux_out) {
  __shared__ int off[N_EXPERTS + 1];
  if (threadIdx.x == 0) {
    int o = 0;
    float aux = 0.f;
    for (int e = 0; e < N_EXPERTS; ++e) {
      off[e] = o;
      o += (cnt[e] + 127) & ~127;
      float d = (float)cnt[e] / (float)NPAIRS - 1.0f / N_EXPERTS;
      aux += d * d;
    }
    off[N_EXPERTS] = o;
    aux_out[0] = aux / N_EXPERTS;
  }
  __syncthreads();
  if (threadIdx.x < N_EXPERTS + 1) offs[threadIdx.x] = off[threadIdx.x];
  for (int b = threadIdx.x; b < MAX_RB; b += 256) {
    int r = b * 128, e = -1;
    for (int j = 0; j < N_EXPERTS; ++j)
      if (r >= off[j] && r < off[j + 1]) e = j;
    rbe[b] = e;
  }
  // zero pad entries so GEMM2 epilogue is branch-free (weight 0 -> adds 0)
  for (int idx = threadIdx.x; idx < N_EXPERTS * 128; idx += 256) {
    int e = idx >> 7, sl = idx & 127;
    int p = off[e] + cnt[e] + sl;
    if (p < off[e + 1]) { rows[p] = 0; wpos[p] = 0.f; }
  }
}

// ---------------- scatter: gather x rows (fp32->bf16) into grouped order ----------------
__global__ __launch_bounds__(256) void scatter_kernel(const float* __restrict__ x,
                                                      const int* __restrict__ tkidx,
                                                      const float* __restrict__ tkw,
                                                      const int* __restrict__ offs,
                                                      int* __restrict__ cursor,
                                                      int* __restrict__ rows,
                                                      float* __restrict__ wpos,
                                                      short* __restrict__ xg) {
  int w = threadIdx.x >> 6, lane = threadIdx.x & 63;
  int pr = blockIdx.x * 4 + w;            // pair index, exactly 32768
  int t = pr >> 1;
  int e = tkidx[pr];
  int p = 0;
  if (lane == 0) {
    p = offs[e] + atomicAdd(&cursor[e], 1);
    rows[p] = t;
    wpos[p] = tkw[pr];
  }
  p = __shfl(p, 0);
  const floatx4* xr = (const floatx4*)(x + (size_t)t * IN_DIM);
  floatx4 a = xr[lane * 2], b = xr[lane * 2 + 1];
  short8 o;
  o[0] = f2bf(a[0]); o[1] = f2bf(a[1]); o[2] = f2bf(a[2]); o[3] = f2bf(a[3]);
  o[4] = f2bf(b[0]); o[5] = f2bf(b[1]); o[6] = f2bf(b[2]); o[7] = f2bf(b[3]);
  *(short8*)(xg + (size_t)p * IN_DIM + lane * 8) = o;
}

// ---------------- grouped GEMM: 128x128 tile, BK=32, 16x16x32 bf16 MFMA ----------------
// MODE 0: H = gelu(A @ W1[e] + b1[e]) -> bf16     (KD=512,  ND=1024)
// MODE 1: atomicAdd(out[tok], w * (A @ W2[e] + b2[e]))   (KD=1024, ND=512)
template <int KD, int ND, int MODE>
__global__ __launch_bounds__(256) void moe_gemm(const short* __restrict__ Amat,
                                                const short* __restrict__ Bmat,
                                                const float* __restrict__ bias,
                                                const int* __restrict__ rbe,
                                                const int* __restrict__ rows,
                                                const float* __restrict__ wpos,
                                                short* __restrict__ Hout,
                                                float* __restrict__ Oout) {
  int e = rbe[blockIdx.y];
  if (e < 0) return;
  const int row0 = blockIdx.y * 128;
  const int n0 = blockIdx.x * 128;
  __shared__ short As[128 * 32];
  __shared__ short Bs[128 * 32];   // [n][k] layout
  const int tid = threadIdx.x;
  const int lane = tid & 63, w = tid >> 6;
  const int wm = w & 1, wn = w >> 1;
  const int mlow = lane & 15, quad = lane >> 4;

  floatx4 acc[4][4] = {};

  const short* gA = Amat + (size_t)(row0 + (tid >> 2)) * KD + (tid & 3) * 8;
  const short* gB = Bmat + (size_t)e * ND * KD + (size_t)(n0 + (tid >> 2)) * KD + (tid & 3) * 8;
  short* lA = As + tid * 8;
  short* lB = Bs + tid * 8;
  const int half = 64 * KD;

  for (int k0 = 0; k0 < KD; k0 += 32) {
    __syncthreads();                       // WAR: prev frag reads done
    async16(gA + k0,        lA);
    async16(gA + k0 + half, lA + 2048);
    async16(gB + k0,        lB);
    async16(gB + k0 + half, lB + 2048);
    __syncthreads();                       // drains vmcnt before barrier
    short8 a[4], b[4];
#pragma unroll
    for (int t = 0; t < 4; ++t) {
      int m = wm * 64 + t * 16 + mlow;
      a[t] = *(const short8*)(As + m * 32 + quad * 8);
      int n = wn * 64 + t * 16 + mlow;
      b[t] = *(const short8*)(Bs + n * 32 + quad * 8);
    }
#pragma unroll
    for (int ti = 0; ti < 4; ++ti)
#pragma unroll
      for (int tj = 0; tj < 4; ++tj)
        acc[ti][tj] = __builtin_amdgcn_mfma_f32_16x16x32_bf16(a[ti], b[tj], acc[ti][tj], 0, 0, 0);
  }

  if (MODE == 0) {
    const float* be = bias + (size_t)e * ND;
#pragma unroll
    for (int ti = 0; ti < 4; ++ti) {
      int gr = row0 + wm * 64 + ti * 16 + quad * 4;
#pragma unroll
      for (int tj = 0; tj < 4; ++tj) {
        int gc = n0 + wn * 64 + tj * 16 + mlow;
        float bv = be[gc];
#pragma unroll
        for (int r = 0; r < 4; ++r) {
          float h = acc[ti][tj][r] + bv;
          float g = 0.5f * h * (1.0f + erff(h * 0.70710678118654752f));
          Hout[(size_t)(gr + r) * ND + gc] = f2bf(g);
        }
      }
    }
  } else {
    const float* be = bias + (size_t)e * ND;
#pragma unroll
    for (int ti = 0; ti < 4; ++ti) {
      int pr = row0 + wm * 64 + ti * 16 + quad * 4;
#pragma unroll
      for (int r = 0; r < 4; ++r) {
        int p = pr + r;
        int tok = rows[p];
        float wt = wpos[p];
#pragma unroll
        for (int tj = 0; tj < 4; ++tj) {
          int gc = n0 + wn * 64 + tj * 16 + mlow;
          float val = wt * (acc[ti][tj][r] + be[gc]);
          atomicAdd(Oout + (size_t)tok * OUT_DIM + gc, val);
        }
      }
    }
  }
}

extern "C" void kernel_launch(void* const* d_in, const int* in_sizes, int n_in,
                              void* d_out, int out_size, void* d_ws, size_t ws_size,
                              hipStream_t stream) {
  const float* x      = (const float*)d_in[0];
  const float* gate_w = (const float*)d_in[1];
  const float* gate_b = (const float*)d_in[2];
  const float* w1     = (const float*)d_in[3];
  const float* b1     = (const float*)d_in[4];
  const float* w2     = (const float*)d_in[5];
  const float* b2     = (const float*)d_in[6];
  float* out = (float*)d_out;
  char* ws = (char*)d_ws;

  int*   cnt    = (int*)(ws + WS_CNT);
  int*   cursor = (int*)(ws + WS_CURSOR);
  int*   offs   = (int*)(ws + WS_OFFS);
  int*   rbe    = (int*)(ws + WS_RBE);
  int*   tkidx  = (int*)(ws + WS_TKIDX);
  float* tkw    = (float*)(ws + WS_TKW);
  int*   rows   = (int*)(ws + WS_ROWS);
  float* wpos   = (float*)(ws + WS_WPOS);
  short* w1t    = (short*)(ws + WS_W1T);
  short* w2t    = (short*)(ws + WS_W2T);
  short* xg     = (short*)(ws + WS_XG);
  short* h      = (short*)(ws + WS_H);

  hipMemsetAsync(ws, 0, 1280, stream);                                   // cnt+cursor(+offs/rbe)
  hipMemsetAsync(d_out, 0, (size_t)out_size * sizeof(float), stream);    // out accumulated by atomics

  transpose_cvt<<<dim3(HID_DIM / 32, IN_DIM / 32, N_EXPERTS), 256, 0, stream>>>(w1, w1t, IN_DIM, HID_DIM);
  transpose_cvt<<<dim3(OUT_DIM / 32, HID_DIM / 32, N_EXPERTS), 256, 0, stream>>>(w2, w2t, HID_DIM, OUT_DIM);

  gate_kernel<<<B_TOKENS / 16, 256, 0, stream>>>(x, gate_w, gate_b, tkidx, tkw, cnt);

  offsets_kernel<<<1, 256, 0, stream>>>(cnt, offs, rbe, rows, wpos, out + (size_t)B_TOKENS * OUT_DIM);

  scatter_kernel<<<NPAIRS / 4, 256, 0, stream>>>(x, tkidx, tkw, offs, cursor, rows, wpos, xg);

  moe_gemm<IN_DIM, HID_DIM, 0><<<dim3(HID_DIM / 128, MAX_RB), 256, 0, stream>>>(
      xg, w1t, b1, rbe, nullptr, nullptr, h, nullptr);

  moe_gemm<HID_DIM, OUT_DIM, 1><<<dim3(OUT_DIM / 128, MAX_RB), 256, 0, stream>>>(
      h, w2t, b2, rbe, rows, wpos, nullptr, out);
}

// Round 2
// 368.469 us; speedup vs baseline: 4.9578x; 4.9578x over previous
//
#include <hip/hip_runtime.h>
#include <hip/hip_bf16.h>
#include <math.h>

#define N_EXPERTS 8
#define TOPK      2
#define IN_DIM    512
#define HID_DIM   1024
#define OUT_DIM   512
#define B_TOKENS  16384
#define NPAIRS    (B_TOKENS * TOPK)   // 32768 token-expert pairs (fixed!)
#define MAX_RB    264                 // max 128-row blocks after per-expert pad
#define MAX_ROWS  (MAX_RB * 128)      // 33792

typedef __attribute__((ext_vector_type(8))) short short8;   // 8 bf16
typedef __attribute__((ext_vector_type(4))) float floatx4;

// ---- workspace layout (bytes) ----
#define WS_CNT     0          // 8 int
#define WS_CURSOR  32         // 8 int
#define WS_OFFS    64         // 9 int
#define WS_RBE     128        // 264 int
#define WS_TKIDX   1280       // 32768 int
#define WS_TKW     132352     // 32768 float
#define WS_ROWS    263424     // 33792 int
#define WS_WPOS    398592     // 33792 float
#define WS_W1T     533760     // 8*1024*512 bf16 = 8 MB
#define WS_W2T     8922368    // 8*512*1024 bf16 = 8 MB
#define WS_XG      17310976   // 33792*512 bf16  = 34.6 MB
#define WS_H       51913984   // 33792*1024 bf16 = 69.2 MB
// total ~121.2 MB

__device__ __forceinline__ short f2bf(float f) {
  unsigned u = __float_as_uint(f);
  unsigned r = (u + 0x7fffu + ((u >> 16) & 1u)) >> 16;  // RNE
  return (short)r;
}

__device__ __forceinline__ void async16(const void* g, void* l) {
  __builtin_amdgcn_global_load_lds(
      (const __attribute__((address_space(1))) unsigned*)g,
      (__attribute__((address_space(3))) unsigned*)l, 16, 0, 0);
}

// ---------------- weight transpose + fp32->bf16 ----------------
// src [E][R][C] fp32 -> dst [E][C][R] bf16
__global__ __launch_bounds__(256) void transpose_cvt(const float* __restrict__ src,
                                                     short* __restrict__ dst,
                                                     int R, int C) {
  __shared__ float tile[32][33];
  int e = blockIdx.z;
  int r0 = blockIdx.y * 32, c0 = blockIdx.x * 32;
  const float* s = src + (size_t)e * R * C;
  short* d = dst + (size_t)e * R * C;
  int tr = threadIdx.x >> 5, tc = threadIdx.x & 31;
#pragma unroll
  for (int j = 0; j < 4; ++j)
    tile[tr + j * 8][tc] = s[(size_t)(r0 + tr + j * 8) * C + c0 + tc];
  __syncthreads();
#pragma unroll
  for (int j = 0; j < 4; ++j)
    d[(size_t)(c0 + tr + j * 8) * R + r0 + tc] = f2bf(tile[tc][tr + j * 8]);
}

// ---------------- gate: fp32 scores, top-2, softmax, counts ----------------
__global__ __launch_bounds__(256) void gate_kernel(const float* __restrict__ x,
                                                   const float* __restrict__ gw,
                                                   const float* __restrict__ gb,
                                                   int* __restrict__ tkidx,
                                                   float* __restrict__ tkw,
                                                   int* __restrict__ cnt) {
  __shared__ int lds_cnt[N_EXPERTS];
  if (threadIdx.x < N_EXPERTS) lds_cnt[threadIdx.x] = 0;
  __syncthreads();
  int w = threadIdx.x >> 6, lane = threadIdx.x & 63;
#pragma unroll 1
  for (int q = 0; q < 4; ++q) {
    int t = blockIdx.x * 16 + w * 4 + q;
    float s[8] = {0.f, 0.f, 0.f, 0.f, 0.f, 0.f, 0.f, 0.f};
#pragma unroll
    for (int it = 0; it < 8; ++it) {
      int i = it * 64 + lane;
      float xv = x[(size_t)t * IN_DIM + i];
      const float4* gwr = (const float4*)(gw + (size_t)i * 8);
      float4 g0 = gwr[0], g1 = gwr[1];
      s[0] += xv * g0.x; s[1] += xv * g0.y; s[2] += xv * g0.z; s[3] += xv * g0.w;
      s[4] += xv * g1.x; s[5] += xv * g1.y; s[6] += xv * g1.z; s[7] += xv * g1.w;
    }
#pragma unroll
    for (int off = 32; off > 0; off >>= 1) {
#pragma unroll
      for (int j = 0; j < 8; ++j) s[j] += __shfl_xor(s[j], off);
    }
    if (lane == 0) {
      float v[8];
#pragma unroll
      for (int j = 0; j < 8; ++j) v[j] = s[j] + gb[j];
      int i1 = 0; float v1 = v[0];
#pragma unroll
      for (int j = 1; j < 8; ++j) if (v[j] > v1) { v1 = v[j]; i1 = j; }
      int i2 = -1; float v2 = -1e30f;
#pragma unroll
      for (int j = 0; j < 8; ++j) if (j != i1 && v[j] > v2) { v2 = v[j]; i2 = j; }
      float ex = expf(v2 - v1);
      float wa = 1.0f / (1.0f + ex);
      tkidx[t * 2] = i1; tkidx[t * 2 + 1] = i2;
      tkw[t * 2] = wa;  tkw[t * 2 + 1] = ex * wa;
      atomicAdd(&lds_cnt[i1], 1); atomicAdd(&lds_cnt[i2], 1);
    }
  }
  __syncthreads();
  if (threadIdx.x < N_EXPERTS) atomicAdd(&cnt[threadIdx.x], lds_cnt[threadIdx.x]);
}

// ---------------- offsets (padded), rb->expert map, pad-entry zero, aux ----------------
__global__ __launch_bounds__(256) void offsets_kernel(const int* __restrict__ cnt,
                                                      int* __restrict__ offs,
                                                      int* __restrict__ rbe,
                                                      int* __restrict__ rows,
                                                      float* __restrict__ wpos,
                                                      float* __restrict__ aux_out) {
  __shared__ int off[N_EXPERTS + 1];
  if (threadIdx.x == 0) {
    int o = 0;
    float aux = 0.f;
    for (int e = 0; e < N_EXPERTS; ++e) {
      off[e] = o;
      o += (cnt[e] + 127) & ~127;
      float d = (float)cnt[e] / (float)NPAIRS - 1.0f / N_EXPERTS;
      aux += d * d;
    }
    off[N_EXPERTS] = o;
    aux_out[0] = aux / N_EXPERTS;
  }
  __syncthreads();
  if (threadIdx.x < N_EXPERTS + 1) offs[threadIdx.x] = off[threadIdx.x];
  for (int b = threadIdx.x; b < MAX_RB; b += 256) {
    int r = b * 128, e = -1;
    for (int j = 0; j < N_EXPERTS; ++j)
      if (r >= off[j] && r < off[j + 1]) e = j;
    rbe[b] = e;
  }
  // zero pad entries so GEMM2 epilogue is branch-free (weight 0 -> adds 0)
  for (int idx = threadIdx.x; idx < N_EXPERTS * 128; idx += 256) {
    int e = idx >> 7, sl = idx & 127;
    int p = off[e] + cnt[e] + sl;
    if (p < off[e + 1]) { rows[p] = 0; wpos[p] = 0.f; }
  }
}

// ---------------- rank: block-aggregated position assignment (8 atomics/block) ----------------
// 32 blocks x 1024 threads; each thread owns one pair. Within-wave rank via
// __ballot, cross-wave scan in LDS, one atomicAdd per (block, expert).
__global__ __launch_bounds__(1024) void rank_kernel(const int* __restrict__ tkidx,
                                                    const float* __restrict__ tkw,
                                                    const int* __restrict__ offs,
                                                    int* __restrict__ cursor,
                                                    int* __restrict__ rows,
                                                    float* __restrict__ wpos) {
  __shared__ int wave_cnt[16][N_EXPERTS];
  __shared__ int wave_base[16][N_EXPERTS];
  __shared__ int blk_base[N_EXPERTS];
  const int tid = threadIdx.x, lane = tid & 63, w = tid >> 6;
  const int pr = blockIdx.x * 1024 + tid;
  const int e = tkidx[pr];
  int myrank = 0;
#pragma unroll
  for (int ei = 0; ei < N_EXPERTS; ++ei) {
    unsigned long long m = __ballot(e == ei);
    if (e == ei) myrank = __popcll(m & ((1ull << lane) - 1ull));
    if (lane == 0) wave_cnt[w][ei] = __popcll(m);
  }
  __syncthreads();
  if (tid < N_EXPERTS) {
    int base = 0;
#pragma unroll
    for (int ww = 0; ww < 16; ++ww) { wave_base[ww][tid] = base; base += wave_cnt[ww][tid]; }
    blk_base[tid] = atomicAdd(&cursor[tid], base);
  }
  __syncthreads();
  const int p = offs[e] + blk_base[e] + wave_base[w][e] + myrank;
  rows[p] = pr >> 1;
  wpos[p] = tkw[pr];
}

// ---------------- copy: gather x rows (fp32->bf16) into grouped order ----------------
// wave per destination row; no atomics. Pad rows copy token 0 (weight is 0).
__global__ __launch_bounds__(256) void copy_kernel(const float* __restrict__ x,
                                                   const int* __restrict__ rows,
                                                   const int* __restrict__ offs,
                                                   short* __restrict__ xg) {
  const int w = threadIdx.x >> 6, lane = threadIdx.x & 63;
  const int p = blockIdx.x * 4 + w;
  if (p >= offs[N_EXPERTS]) return;
  const int t = rows[p];
  const floatx4* xr = (const floatx4*)(x + (size_t)t * IN_DIM);
  floatx4 a = xr[lane * 2], b = xr[lane * 2 + 1];
  short8 o;
  o[0] = f2bf(a[0]); o[1] = f2bf(a[1]); o[2] = f2bf(a[2]); o[3] = f2bf(a[3]);
  o[4] = f2bf(b[0]); o[5] = f2bf(b[1]); o[6] = f2bf(b[2]); o[7] = f2bf(b[3]);
  *(short8*)(xg + (size_t)p * IN_DIM + lane * 8) = o;
}

// ---------------- grouped GEMM: 128x128 tile, BK=32, 16x16x32 bf16 MFMA ----------------
// MODE 0: H = gelu(A @ W1[e] + b1[e]) -> bf16     (KD=512,  ND=1024)
// MODE 1: atomicAdd(out[tok], w * (A @ W2[e] + b2[e]))   (KD=1024, ND=512)
template <int KD, int ND, int MODE>
__global__ __launch_bounds__(256) void moe_gemm(const short* __restrict__ Amat,
                                                const short* __restrict__ Bmat,
                                                const float* __restrict__ bias,
                                                const int* __restrict__ rbe,
                                                const int* __restrict__ rows,
                                                const float* __restrict__ wpos,
                                                short* __restrict__ Hout,
                                                float* __restrict__ Oout) {
  int e = rbe[blockIdx.y];
  if (e < 0) return;
  const int row0 = blockIdx.y * 128;
  const int n0 = blockIdx.x * 128;
  __shared__ short As[128 * 32];
  __shared__ short Bs[128 * 32];   // [n][k] layout
  const int tid = threadIdx.x;
  const int lane = tid & 63, w = tid >> 6;
  const int wm = w & 1, wn = w >> 1;
  const int mlow = lane & 15, quad = lane >> 4;

  floatx4 acc[4][4] = {};

  const short* gA = Amat + (size_t)(row0 + (tid >> 2)) * KD + (tid & 3) * 8;
  const short* gB = Bmat + (size_t)e * ND * KD + (size_t)(n0 + (tid >> 2)) * KD + (tid & 3) * 8;
  short* lA = As + tid * 8;
  short* lB = Bs + tid * 8;
  const int half = 64 * KD;

  for (int k0 = 0; k0 < KD; k0 += 32) {
    __syncthreads();                       // WAR: prev frag reads done
    async16(gA + k0,        lA);
    async16(gA + k0 + half, lA + 2048);
    async16(gB + k0,        lB);
    async16(gB + k0 + half, lB + 2048);
    __syncthreads();                       // drains vmcnt before barrier
    short8 a[4], b[4];
#pragma unroll
    for (int t = 0; t < 4; ++t) {
      int m = wm * 64 + t * 16 + mlow;
      a[t] = *(const short8*)(As + m * 32 + quad * 8);
      int n = wn * 64 + t * 16 + mlow;
      b[t] = *(const short8*)(Bs + n * 32 + quad * 8);
    }
#pragma unroll
    for (int ti = 0; ti < 4; ++ti)
#pragma unroll
      for (int tj = 0; tj < 4; ++tj)
        acc[ti][tj] = __builtin_amdgcn_mfma_f32_16x16x32_bf16(a[ti], b[tj], acc[ti][tj], 0, 0, 0);
  }

  if (MODE == 0) {
    const float* be = bias + (size_t)e * ND;
#pragma unroll
    for (int ti = 0; ti < 4; ++ti) {
      int gr = row0 + wm * 64 + ti * 16 + quad * 4;
#pragma unroll
      for (int tj = 0; tj < 4; ++tj) {
        int gc = n0 + wn * 64 + tj * 16 + mlow;
        float bv = be[gc];
#pragma unroll
        for (int r = 0; r < 4; ++r) {
          float h = acc[ti][tj][r] + bv;
          float g = 0.5f * h * (1.0f + erff(h * 0.70710678118654752f));
          Hout[(size_t)(gr + r) * ND + gc] = f2bf(g);
        }
      }
    }
  } else {
    const float* be = bias + (size_t)e * ND;
#pragma unroll
    for (int ti = 0; ti < 4; ++ti) {
      int pr = row0 + wm * 64 + ti * 16 + quad * 4;
#pragma unroll
      for (int r = 0; r < 4; ++r) {
        int p = pr + r;
        int tok = rows[p];
        float wt = wpos[p];
#pragma unroll
        for (int tj = 0; tj < 4; ++tj) {
          int gc = n0 + wn * 64 + tj * 16 + mlow;
          float val = wt * (acc[ti][tj][r] + be[gc]);
          atomicAdd(Oout + (size_t)tok * OUT_DIM + gc, val);
        }
      }
    }
  }
}

extern "C" void kernel_launch(void* const* d_in, const int* in_sizes, int n_in,
                              void* d_out, int out_size, void* d_ws, size_t ws_size,
                              hipStream_t stream) {
  const float* x      = (const float*)d_in[0];
  const float* gate_w = (const float*)d_in[1];
  const float* gate_b = (const float*)d_in[2];
  const float* w1     = (const float*)d_in[3];
  const float* b1     = (const float*)d_in[4];
  const float* w2     = (const float*)d_in[5];
  const float* b2     = (const float*)d_in[6];
  float* out = (float*)d_out;
  char* ws = (char*)d_ws;

  int*   cnt    = (int*)(ws + WS_CNT);
  int*   cursor = (int*)(ws + WS_CURSOR);
  int*   offs   = (int*)(ws + WS_OFFS);
  int*   rbe    = (int*)(ws + WS_RBE);
  int*   tkidx  = (int*)(ws + WS_TKIDX);
  float* tkw    = (float*)(ws + WS_TKW);
  int*   rows   = (int*)(ws + WS_ROWS);
  float* wpos   = (float*)(ws + WS_WPOS);
  short* w1t    = (short*)(ws + WS_W1T);
  short* w2t    = (short*)(ws + WS_W2T);
  short* xg     = (short*)(ws + WS_XG);
  short* h      = (short*)(ws + WS_H);

  hipMemsetAsync(ws, 0, 1280, stream);                                   // cnt+cursor+offs+rbe
  hipMemsetAsync(d_out, 0, (size_t)out_size * sizeof(float), stream);    // out accumulated by atomics

  transpose_cvt<<<dim3(HID_DIM / 32, IN_DIM / 32, N_EXPERTS), 256, 0, stream>>>(w1, w1t, IN_DIM, HID_DIM);
  transpose_cvt<<<dim3(OUT_DIM / 32, HID_DIM / 32, N_EXPERTS), 256, 0, stream>>>(w2, w2t, HID_DIM, OUT_DIM);

  gate_kernel<<<B_TOKENS / 16, 256, 0, stream>>>(x, gate_w, gate_b, tkidx, tkw, cnt);

  offsets_kernel<<<1, 256, 0, stream>>>(cnt, offs, rbe, rows, wpos, out + (size_t)B_TOKENS * OUT_DIM);

  rank_kernel<<<NPAIRS / 1024, 1024, 0, stream>>>(tkidx, tkw, offs, cursor, rows, wpos);

  copy_kernel<<<MAX_ROWS / 4, 256, 0, stream>>>(x, rows, offs, xg);

  moe_gemm<IN_DIM, HID_DIM, 0><<<dim3(HID_DIM / 128, MAX_RB), 256, 0, stream>>>(
      xg, w1t, b1, rbe, nullptr, nullptr, h, nullptr);

  moe_gemm<HID_DIM, OUT_DIM, 1><<<dim3(OUT_DIM / 128, MAX_RB), 256, 0, stream>>>(
      h, w2t, b2, rbe, rows, wpos, nullptr, out);
}

// Round 3
// 367.548 us; speedup vs baseline: 4.9702x; 1.0025x over previous
//
#include <hip/hip_runtime.h>
#include <hip/hip_bf16.h>
#include <math.h>

#define N_EXPERTS 8
#define TOPK      2
#define IN_DIM    512
#define HID_DIM   1024
#define OUT_DIM   512
#define B_TOKENS  16384
#define NPAIRS    (B_TOKENS * TOPK)   // 32768 token-expert pairs (fixed!)
#define MAX_RB    264                 // max 128-row blocks after per-expert pad
#define MAX_ROWS  (MAX_RB * 128)      // 33792

typedef __attribute__((ext_vector_type(8))) short short8;   // 8 bf16
typedef __attribute__((ext_vector_type(4))) float floatx4;

// ---- workspace layout (bytes) ----
#define WS_CNT     0          // 8 int
#define WS_CURSOR  32         // 8 int
#define WS_OFFS    64         // 9 int
#define WS_RBE     128        // 264 int
#define WS_TKIDX   1280       // 32768 int
#define WS_TKW     132352     // 32768 float
#define WS_ROWS    263424     // 33792 int
#define WS_WPOS    398592     // 33792 float
#define WS_W1T     533760     // 8*1024*512 bf16 = 8 MB
#define WS_W2T     8922368    // 8*512*1024 bf16 = 8 MB
#define WS_XG      17310976   // 33792*512 bf16  = 34.6 MB
#define WS_H       51913984   // 33792*1024 bf16 = 69.2 MB
// total ~121.2 MB

__device__ __forceinline__ short f2bf(float f) {
  unsigned u = __float_as_uint(f);
  unsigned r = (u + 0x7fffu + ((u >> 16) & 1u)) >> 16;  // RNE
  return (short)r;
}

// ---------------- weight transpose + fp32->bf16 ----------------
// src [E][R][C] fp32 -> dst [E][C][R] bf16
__global__ __launch_bounds__(256) void transpose_cvt(const float* __restrict__ src,
                                                     short* __restrict__ dst,
                                                     int R, int C) {
  __shared__ float tile[32][33];
  int e = blockIdx.z;
  int r0 = blockIdx.y * 32, c0 = blockIdx.x * 32;
  const float* s = src + (size_t)e * R * C;
  short* d = dst + (size_t)e * R * C;
  int tr = threadIdx.x >> 5, tc = threadIdx.x & 31;
#pragma unroll
  for (int j = 0; j < 4; ++j)
    tile[tr + j * 8][tc] = s[(size_t)(r0 + tr + j * 8) * C + c0 + tc];
  __syncthreads();
#pragma unroll
  for (int j = 0; j < 4; ++j)
    d[(size_t)(c0 + tr + j * 8) * R + r0 + tc] = f2bf(tile[tc][tr + j * 8]);
}

// ---------------- gate: fp32 scores, top-2, softmax, counts ----------------
__global__ __launch_bounds__(256) void gate_kernel(const float* __restrict__ x,
                                                   const float* __restrict__ gw,
                                                   const float* __restrict__ gb,
                                                   int* __restrict__ tkidx,
                                                   float* __restrict__ tkw,
                                                   int* __restrict__ cnt) {
  __shared__ int lds_cnt[N_EXPERTS];
  if (threadIdx.x < N_EXPERTS) lds_cnt[threadIdx.x] = 0;
  __syncthreads();
  int w = threadIdx.x >> 6, lane = threadIdx.x & 63;
#pragma unroll 1
  for (int q = 0; q < 4; ++q) {
    int t = blockIdx.x * 16 + w * 4 + q;
    float s[8] = {0.f, 0.f, 0.f, 0.f, 0.f, 0.f, 0.f, 0.f};
#pragma unroll
    for (int it = 0; it < 8; ++it) {
      int i = it * 64 + lane;
      float xv = x[(size_t)t * IN_DIM + i];
      const float4* gwr = (const float4*)(gw + (size_t)i * 8);
      float4 g0 = gwr[0], g1 = gwr[1];
      s[0] += xv * g0.x; s[1] += xv * g0.y; s[2] += xv * g0.z; s[3] += xv * g0.w;
      s[4] += xv * g1.x; s[5] += xv * g1.y; s[6] += xv * g1.z; s[7] += xv * g1.w;
    }
#pragma unroll
    for (int off = 32; off > 0; off >>= 1) {
#pragma unroll
      for (int j = 0; j < 8; ++j) s[j] += __shfl_xor(s[j], off);
    }
    if (lane == 0) {
      float v[8];
#pragma unroll
      for (int j = 0; j < 8; ++j) v[j] = s[j] + gb[j];
      int i1 = 0; float v1 = v[0];
#pragma unroll
      for (int j = 1; j < 8; ++j) if (v[j] > v1) { v1 = v[j]; i1 = j; }
      int i2 = -1; float v2 = -1e30f;
#pragma unroll
      for (int j = 0; j < 8; ++j) if (j != i1 && v[j] > v2) { v2 = v[j]; i2 = j; }
      float ex = expf(v2 - v1);
      float wa = 1.0f / (1.0f + ex);
      tkidx[t * 2] = i1; tkidx[t * 2 + 1] = i2;
      tkw[t * 2] = wa;  tkw[t * 2 + 1] = ex * wa;
      atomicAdd(&lds_cnt[i1], 1); atomicAdd(&lds_cnt[i2], 1);
    }
  }
  __syncthreads();
  if (threadIdx.x < N_EXPERTS) atomicAdd(&cnt[threadIdx.x], lds_cnt[threadIdx.x]);
}

// ---------------- offsets (padded), rb->expert map, pad-entry zero, aux ----------------
__global__ __launch_bounds__(256) void offsets_kernel(const int* __restrict__ cnt,
                                                      int* __restrict__ offs,
                                                      int* __restrict__ rbe,
                                                      int* __restrict__ rows,
                                                      float* __restrict__ wpos,
                                                      float* __restrict__ aux_out) {
  __shared__ int off[N_EXPERTS + 1];
  if (threadIdx.x == 0) {
    int o = 0;
    float aux = 0.f;
    for (int e = 0; e < N_EXPERTS; ++e) {
      off[e] = o;
      o += (cnt[e] + 127) & ~127;
      float d = (float)cnt[e] / (float)NPAIRS - 1.0f / N_EXPERTS;
      aux += d * d;
    }
    off[N_EXPERTS] = o;
    aux_out[0] = aux / N_EXPERTS;
  }
  __syncthreads();
  if (threadIdx.x < N_EXPERTS + 1) offs[threadIdx.x] = off[threadIdx.x];
  for (int b = threadIdx.x; b < MAX_RB; b += 256) {
    int r = b * 128, e = -1;
    for (int j = 0; j < N_EXPERTS; ++j)
      if (r >= off[j] && r < off[j + 1]) e = j;
    rbe[b] = e;
  }
  // zero pad entries so GEMM2 epilogue is branch-free (weight 0 -> adds 0)
  for (int idx = threadIdx.x; idx < N_EXPERTS * 128; idx += 256) {
    int e = idx >> 7, sl = idx & 127;
    int p = off[e] + cnt[e] + sl;
    if (p < off[e + 1]) { rows[p] = 0; wpos[p] = 0.f; }
  }
}

// ---------------- rank: block-aggregated position assignment (8 atomics/block) ----------------
__global__ __launch_bounds__(1024) void rank_kernel(const int* __restrict__ tkidx,
                                                    const float* __restrict__ tkw,
                                                    const int* __restrict__ offs,
                                                    int* __restrict__ cursor,
                                                    int* __restrict__ rows,
                                                    float* __restrict__ wpos) {
  __shared__ int wave_cnt[16][N_EXPERTS];
  __shared__ int wave_base[16][N_EXPERTS];
  __shared__ int blk_base[N_EXPERTS];
  const int tid = threadIdx.x, lane = tid & 63, w = tid >> 6;
  const int pr = blockIdx.x * 1024 + tid;
  const int e = tkidx[pr];
  int myrank = 0;
#pragma unroll
  for (int ei = 0; ei < N_EXPERTS; ++ei) {
    unsigned long long m = __ballot(e == ei);
    if (e == ei) myrank = __popcll(m & ((1ull << lane) - 1ull));
    if (lane == 0) wave_cnt[w][ei] = __popcll(m);
  }
  __syncthreads();
  if (tid < N_EXPERTS) {
    int base = 0;
#pragma unroll
    for (int ww = 0; ww < 16; ++ww) { wave_base[ww][tid] = base; base += wave_cnt[ww][tid]; }
    blk_base[tid] = atomicAdd(&cursor[tid], base);
  }
  __syncthreads();
  const int p = offs[e] + blk_base[e] + wave_base[w][e] + myrank;
  rows[p] = pr >> 1;
  wpos[p] = tkw[pr];
}

// ---------------- copy: gather x rows (fp32->bf16) into grouped order ----------------
__global__ __launch_bounds__(256) void copy_kernel(const float* __restrict__ x,
                                                   const int* __restrict__ rows,
                                                   const int* __restrict__ offs,
                                                   short* __restrict__ xg) {
  const int w = threadIdx.x >> 6, lane = threadIdx.x & 63;
  const int p = blockIdx.x * 4 + w;
  if (p >= offs[N_EXPERTS]) return;
  const int t = rows[p];
  const floatx4* xr = (const floatx4*)(x + (size_t)t * IN_DIM);
  floatx4 a = xr[lane * 2], b = xr[lane * 2 + 1];
  short8 o;
  o[0] = f2bf(a[0]); o[1] = f2bf(a[1]); o[2] = f2bf(a[2]); o[3] = f2bf(a[3]);
  o[4] = f2bf(b[0]); o[5] = f2bf(b[1]); o[6] = f2bf(b[2]); o[7] = f2bf(b[3]);
  *(short8*)(xg + (size_t)p * IN_DIM + lane * 8) = o;
}

// ---------------- grouped GEMM: 128x128 tile, BK=64, register-prefetch pipeline ----------------
// LDS is "fragment-major": chunk c = t*128 + kk*64 + quad*16 + mlow holds
// M[t*16+mlow][k0 + kk*32 + quad*8 .. +8]. Lane-consecutive 16B chunks on both
// ds_write (staging) and ds_read (frags) -> conflict-free.
// MODE 0: H = gelu(A @ W1[e] + b1[e]) -> bf16     (KD=512,  ND=1024)
// MODE 1: atomicAdd(out[tok], w * (A @ W2[e] + b2[e]))   (KD=1024, ND=512)
template <int KD, int ND, int MODE>
__global__ __launch_bounds__(256) void moe_gemm(const short* __restrict__ Amat,
                                                const short* __restrict__ Bmat,
                                                const float* __restrict__ bias,
                                                const int* __restrict__ rbe,
                                                const int* __restrict__ rows,
                                                const float* __restrict__ wpos,
                                                short* __restrict__ Hout,
                                                float* __restrict__ Oout) {
  int e = rbe[blockIdx.y];
  if (e < 0) return;
  const int row0 = blockIdx.y * 128;
  const int n0 = blockIdx.x * 128;
  __shared__ short As[128 * 64];   // 16 KB, fragment-major
  __shared__ short Bs[128 * 64];   // 16 KB
  const int tid = threadIdx.x;
  const int lane = tid & 63, w = tid >> 6;
  const int wm = w & 1, wn = w >> 1;
  const int mlow = lane & 15, quad = lane >> 4;

  floatx4 acc[4][4] = {};

  // staging: thread tid owns row srow, k-half skp (32 shorts = 64B contiguous)
  const int srow = tid >> 1, skp = tid & 1;
  const short* gA = Amat + (size_t)(row0 + srow) * KD + skp * 32;
  const short* gB = Bmat + (size_t)e * ND * KD + (size_t)(n0 + srow) * KD + skp * 32;
  // LDS dest chunks: c(q) = (srow>>4)*128 + skp*64 + q*16 + (srow&15)
  const int wbase = (((srow >> 4) * 128 + skp * 64 + (srow & 15))) * 8;  // shorts

  short8 pa[4], pb[4];
#pragma unroll
  for (int q = 0; q < 4; ++q) {
    pa[q] = *(const short8*)(gA + q * 8);
    pb[q] = *(const short8*)(gB + q * 8);
  }

  for (int k0 = 0; k0 < KD; k0 += 64) {
    __syncthreads();                       // WAR: prev frag reads done
#pragma unroll
    for (int q = 0; q < 4; ++q) {
      *(short8*)(As + wbase + q * 128) = pa[q];
      *(short8*)(Bs + wbase + q * 128) = pb[q];
    }
    if (k0 + 64 < KD) {
#pragma unroll
      for (int q = 0; q < 4; ++q) {
        pa[q] = *(const short8*)(gA + k0 + 64 + q * 8);
        pb[q] = *(const short8*)(gB + k0 + 64 + q * 8);
      }
    }
    __syncthreads();                       // writes visible
#pragma unroll
    for (int kk = 0; kk < 2; ++kk) {
      short8 a[4], b[4];
#pragma unroll
      for (int t = 0; t < 4; ++t) {
        a[t] = *(const short8*)(As + ((wm * 4 + t) * 128 + kk * 64 + quad * 16 + mlow) * 8);
        b[t] = *(const short8*)(Bs + ((wn * 4 + t) * 128 + kk * 64 + quad * 16 + mlow) * 8);
      }
#pragma unroll
      for (int ti = 0; ti < 4; ++ti)
#pragma unroll
        for (int tj = 0; tj < 4; ++tj)
          acc[ti][tj] = __builtin_amdgcn_mfma_f32_16x16x32_bf16(a[ti], b[tj], acc[ti][tj], 0, 0, 0);
    }
  }

  if (MODE == 0) {
    const float* be = bias + (size_t)e * ND;
#pragma unroll
    for (int ti = 0; ti < 4; ++ti) {
      int gr = row0 + wm * 64 + ti * 16 + quad * 4;
#pragma unroll
      for (int tj = 0; tj < 4; ++tj) {
        int gc = n0 + wn * 64 + tj * 16 + mlow;
        float bv = be[gc];
#pragma unroll
        for (int r = 0; r < 4; ++r) {
          float h = acc[ti][tj][r] + bv;
          float g = 0.5f * h * (1.0f + erff(h * 0.70710678118654752f));
          Hout[(size_t)(gr + r) * ND + gc] = f2bf(g);
        }
      }
    }
  } else {
    const float* be = bias + (size_t)e * ND;
#pragma unroll
    for (int ti = 0; ti < 4; ++ti) {
      int pr = row0 + wm * 64 + ti * 16 + quad * 4;
#pragma unroll
      for (int r = 0; r < 4; ++r) {
        int p = pr + r;
        int tok = rows[p];
        float wt = wpos[p];
#pragma unroll
        for (int tj = 0; tj < 4; ++tj) {
          int gc = n0 + wn * 64 + tj * 16 + mlow;
          float val = wt * (acc[ti][tj][r] + be[gc]);
          atomicAdd(Oout + (size_t)tok * OUT_DIM + gc, val);
        }
      }
    }
  }
}

extern "C" void kernel_launch(void* const* d_in, const int* in_sizes, int n_in,
                              void* d_out, int out_size, void* d_ws, size_t ws_size,
                              hipStream_t stream) {
  const float* x      = (const float*)d_in[0];
  const float* gate_w = (const float*)d_in[1];
  const float* gate_b = (const float*)d_in[2];
  const float* w1     = (const float*)d_in[3];
  const float* b1     = (const float*)d_in[4];
  const float* w2     = (const float*)d_in[5];
  const float* b2     = (const float*)d_in[6];
  float* out = (float*)d_out;
  char* ws = (char*)d_ws;

  int*   cnt    = (int*)(ws + WS_CNT);
  int*   cursor = (int*)(ws + WS_CURSOR);
  int*   offs   = (int*)(ws + WS_OFFS);
  int*   rbe    = (int*)(ws + WS_RBE);
  int*   tkidx  = (int*)(ws + WS_TKIDX);
  float* tkw    = (float*)(ws + WS_TKW);
  int*   rows   = (int*)(ws + WS_ROWS);
  float* wpos   = (float*)(ws + WS_WPOS);
  short* w1t    = (short*)(ws + WS_W1T);
  short* w2t    = (short*)(ws + WS_W2T);
  short* xg     = (short*)(ws + WS_XG);
  short* h      = (short*)(ws + WS_H);

  hipMemsetAsync(ws, 0, 1280, stream);                                   // cnt+cursor+offs+rbe
  hipMemsetAsync(d_out, 0, (size_t)out_size * sizeof(float), stream);    // out accumulated by atomics

  transpose_cvt<<<dim3(HID_DIM / 32, IN_DIM / 32, N_EXPERTS), 256, 0, stream>>>(w1, w1t, IN_DIM, HID_DIM);
  transpose_cvt<<<dim3(OUT_DIM / 32, HID_DIM / 32, N_EXPERTS), 256, 0, stream>>>(w2, w2t, HID_DIM, OUT_DIM);

  gate_kernel<<<B_TOKENS / 16, 256, 0, stream>>>(x, gate_w, gate_b, tkidx, tkw, cnt);

  offsets_kernel<<<1, 256, 0, stream>>>(cnt, offs, rbe, rows, wpos, out + (size_t)B_TOKENS * OUT_DIM);

  rank_kernel<<<NPAIRS / 1024, 1024, 0, stream>>>(tkidx, tkw, offs, cursor, rows, wpos);

  copy_kernel<<<MAX_ROWS / 4, 256, 0, stream>>>(x, rows, offs, xg);

  moe_gemm<IN_DIM, HID_DIM, 0><<<dim3(HID_DIM / 128, MAX_RB), 256, 0, stream>>>(
      xg, w1t, b1, rbe, nullptr, nullptr, h, nullptr);

  moe_gemm<HID_DIM, OUT_DIM, 1><<<dim3(OUT_DIM / 128, MAX_RB), 256, 0, stream>>>(
      h, w2t, b2, rbe, rows, wpos, nullptr, out);
}